// Round 3
// baseline (476.937 us; speedup 1.0000x reference)
//
#include <hip/hip_runtime.h>
#include <math.h>

typedef unsigned short u16;
typedef unsigned int u32;
typedef __bf16 bf16x8 __attribute__((ext_vector_type(8)));
typedef float f32x4 __attribute__((ext_vector_type(4)));

#define NL 41
#define HW 16384

// ws layout (bytes). partials/sums overlay NHWC (dead after k_conv).
#define NHWC_OFF   0            // 8*16384*256 bf16 = 67,108,864 B
#define PART_OFF   0            // 8*2*41*64*128 f32 = 21,495,808 B (after conv)
#define SUMS_OFF   21495808     // 8*2*41*128 f32 = 335,872 B
#define WA_OFF     67108864     // 576*64*8 bf16 = 589,824 B
#define GHIST_OFF  67698688     // 8*41 int
#define GATES_OFF  67700224     // 2*8*128 f32

__device__ __forceinline__ u16 f2bf(float f) {
    u32 u = __builtin_bit_cast(u32, f);
    u = (u + 0x7FFFu + ((u >> 16) & 1u)) >> 16;
    return (u16)u;
}

__device__ __forceinline__ void glds16(const void* g, void* l) {
    __builtin_amdgcn_global_load_lds(
        (const __attribute__((address_space(1))) void*)g,
        (__attribute__((address_space(3))) void*)l, 16, 0, 0);
}

// ---------------------------------------------------------------------------
// K0: fused add/mul -> bf16 NHWC [b][px][c'] (c'<128 = r+d, 128+c = r*sig(d)).
// 2048 blocks (8b x 256 chunks of 64 px), 256 thr, 32 KB LDS -> 4 blocks/CU.
// ---------------------------------------------------------------------------
__global__ __launch_bounds__(256, 4)
void k_prep(const float* __restrict__ r, const float* __restrict__ d,
            u16* __restrict__ nhwc)
{
    __shared__ u16 s[64 * 256];             // [px][c'] 32 KB
    const int bid = (int)blockIdx.x;
    const int b = bid >> 8;
    const int px0 = (bid & 255) * 64;
    const int tid = (int)threadIdx.x;
    const int c = tid & 127;
    const int half = tid >> 7;              // px half 0/1

    const float* rp = r + ((size_t)(b * 128 + c)) * HW + px0 + half * 32;
    const float* dp = d + ((size_t)(b * 128 + c)) * HW + px0 + half * 32;
#pragma unroll
    for (int j = 0; j < 8; ++j) {
        float4 rv = *(const float4*)(rp + j * 4);
        float4 dv = *(const float4*)(dp + j * 4);
        float ra[4] = {rv.x, rv.y, rv.z, rv.w};
        float da[4] = {dv.x, dv.y, dv.z, dv.w};
#pragma unroll
        for (int i = 0; i < 4; ++i) {
            int px = half * 32 + j * 4 + i;
            s[px * 256 + c] = f2bf(ra[i] + da[i]);
            s[px * 256 + 128 + c] = f2bf(ra[i] / (1.f + __expf(-da[i])));
        }
    }
    __syncthreads();
    const f32x4* sf = (const f32x4*)s;
    f32x4* dst = (f32x4*)nhwc + ((size_t)b * HW + px0) * 32;
#pragma unroll
    for (int k = 0; k < 8; ++k) {
        int fi = k * 256 + tid;             // granule index, 2048 total
        dst[fi] = sf[fi];
    }
}

// ---------------------------------------------------------------------------
// K0b: weight repack -> Wa[kt*8+ct][lane][8] bf16; co=l&15, cin=chunk*32+(l>>4)*8+j.
// Block 0 also zeroes the global label histogram (runs before k_seg).
// ---------------------------------------------------------------------------
__global__ __launch_bounds__(64)
void k_wpack(const float* __restrict__ w, u16* __restrict__ wa, int* __restrict__ ghist)
{
    const int bid = (int)blockIdx.x;        // kt*8 + ct, 576 blocks
    const int l = (int)threadIdx.x;
    if (bid == 0) {
        for (int i = l; i < 8 * NL; i += 64) ghist[i] = 0;
    }
    const int kt = bid >> 3, ct = bid & 7;
    const int chunk = kt / 9, tap = kt - chunk * 9;
    const int co = ct * 16 + (l & 15);
    const int cin0 = chunk * 32 + (l >> 4) * 8;
    u16 tmp[8];
#pragma unroll
    for (int j = 0; j < 8; ++j)
        tmp[j] = f2bf(w[((size_t)co * 256 + cin0 + j) * 9 + tap]);
    *(f32x4*)&wa[((size_t)bid * 64 + l) * 8] = *(f32x4*)tmp;
}

// ---------------------------------------------------------------------------
// K1: conv3x3 implicit GEMM, bf16 MFMA 16x16x32.
// Block: 1 row x 128 x x 128 co, 4 waves = (xh, wc), wave tile 64co x 64px,
// acc = 64 regs -> 4 waves/SIMD. grid 1024, bid = y*8 + b (XCD: batch-per-die).
// LDS: 3 rows x 130 x-slots x (stride 5 granules: 4 ci8 + 1 pad) = 31.2 KB.
// Stride-5 makes B-frag ds_read_b128 bank-phase = 5x mod 8 -> 2-way (free).
// ---------------------------------------------------------------------------
__global__ __launch_bounds__(256, 4)
void k_conv(const u16* __restrict__ nhwc, const u16* __restrict__ wa,
            float* __restrict__ out)
{
    __shared__ u16 s_in[1950 * 8];          // 31200 B, granule(row,x,ci8)=row*650+x*5+ci8
    const int tid = (int)threadIdx.x;
    const int bid = (int)blockIdx.x;
    const int b = bid & 7;
    const int y0 = bid >> 3;
    const int l = tid & 63;
    const int wv = tid >> 6;
    const int xh = wv & 1;
    const int wc = wv >> 1;
    const int l15 = l & 15;
    const int l16 = l >> 4;

    {   // zero all granules once; staging only overwrites in-image ones
        f32x4 zz = {0.f, 0.f, 0.f, 0.f};
        for (int i = tid; i < 1950; i += 256) ((f32x4*)s_in)[i] = zz;
    }

    // per-lane global byte offsets for the 8 staging rounds (-1 = masked)
    int goff[8];
#pragma unroll
    for (int it = 0; it < 8; ++it) {
        int s = it * 256 + tid;
        int row = s / 650;
        int rem = s - row * 650;
        int x = rem / 5;
        int ci8 = rem - x * 5;
        int gy = y0 - 1 + row;
        int gx = x - 1;
        bool valid = (s < 1950) && (ci8 < 4) &&
                     ((unsigned)gy < 128u) && ((unsigned)gx < 128u);
        goff[it] = valid ? (((gy << 7) | gx) * 256 + ci8 * 8) * 2 : -1;
    }

    f32x4 acc[4][4];
#pragma unroll
    for (int i = 0; i < 4; ++i)
#pragma unroll
        for (int j = 0; j < 4; ++j) {
            f32x4 zz = {0.f, 0.f, 0.f, 0.f};
            acc[i][j] = zz;
        }

    const char* src_b = (const char*)(nhwc + (size_t)b * HW * 256);
    const int base0 = (xh * 64 + l15) * 80 + l16 * 16;  // byte addr in LDS
    const int lds_wbase = (tid & 192) * 16;             // wave-uniform

#pragma unroll 1
    for (int chunk = 0; chunk < 8; ++chunk) {
        __syncthreads();
#pragma unroll
        for (int it = 0; it < 8; ++it) {
            if (goff[it] >= 0)
                glds16(src_b + goff[it] + chunk * 64,
                       (char*)s_in + it * 4096 + lds_wbase);
        }
        __syncthreads();

        const u16* wch = wa + (size_t)(chunk * 72) * 512;   // (kt*8+ct)*64*8 elems
#pragma unroll
        for (int tap = 0; tap < 9; ++tap) {
            f32x4 a[4];
#pragma unroll
            for (int i = 0; i < 4; ++i)
                a[i] = *(const f32x4*)&wch[((tap * 8 + wc * 4 + i) * 64 + l) * 8];
            const int off = (tap / 3) * 10400 + (tap % 3) * 80;
            f32x4 bf[4];
#pragma unroll
            for (int p = 0; p < 4; ++p)
                bf[p] = *(const f32x4*)((const char*)s_in + base0 + off + p * 1280);
#pragma unroll
            for (int ct = 0; ct < 4; ++ct) {
                bf16x8 av = __builtin_bit_cast(bf16x8, a[ct]);
#pragma unroll
                for (int p = 0; p < 4; ++p)
                    acc[ct][p] = __builtin_amdgcn_mfma_f32_16x16x32_bf16(
                        av, __builtin_bit_cast(bf16x8, bf[p]), acc[ct][p], 0, 0, 0);
            }
        }
    }

    // D: col = px = l&15, row = co = (l>>4)*4 + reg
    float* outb = out + (size_t)b * 128 * HW + (size_t)y0 * 128;
#pragma unroll
    for (int ct = 0; ct < 4; ++ct)
#pragma unroll
        for (int p = 0; p < 4; ++p) {
            int x = xh * 64 + p * 16 + l15;
#pragma unroll
            for (int rr = 0; rr < 4; ++rr) {
                int co = wc * 64 + ct * 16 + l16 * 4 + rr;
                outb[(size_t)co * HW + x] = acc[ct][p][rr];
            }
        }
}

// ---------------------------------------------------------------------------
// K2: segment partial sums for fuse (threads 0-127) and d (threads 128-255),
// 512 blocks = 8b x 64 chunks of 256 px. Thread owns channel column -> no
// atomics, 2-way LDS bank aliasing (free). Also counts labels into ghist.
// ---------------------------------------------------------------------------
__global__ __launch_bounds__(256, 2)
void k_seg(const float* __restrict__ fuse, const float* __restrict__ d,
           const int* __restrict__ label, float* __restrict__ partials,
           int* __restrict__ ghist)
{
    __shared__ float bins[2][NL][128];
    __shared__ int hist[NL];
    const int b = (int)blockIdx.x & 7;
    const int chunk = (int)blockIdx.x >> 3;
    const int tid = (int)threadIdx.x;
    const int c = tid & 127;
    const int g = tid >> 7;

#pragma unroll
    for (int i = 0; i < NL; ++i) bins[g][i][c] = 0.f;
    if (tid < NL) hist[tid] = 0;
    __syncthreads();

    const float* src = (g ? d : fuse) + ((size_t)(b * 128 + c)) * HW;
    const int* lp = label + (size_t)b * 512 * 512;
    const int p0 = chunk * 256;

    // label count (wave 0 only; labels are block-uniform)
    if (tid < 64) {
#pragma unroll
        for (int rep = 0; rep < 4; ++rep) {
            int p = p0 + rep * 64 + tid;
            int y = p >> 7, x = p & 127;
            atomicAdd(&hist[lp[(y * 4) * 512 + x * 4]], 1);
        }
    }

    for (int i = 0; i < 256; i += 4) {
        int p = p0 + i;
        int y = p >> 7, x = p & 127;
        const int* lrow = lp + (y * 4) * 512 + x * 4;
        int l0 = lrow[0], l1 = lrow[4], l2 = lrow[8], l3 = lrow[12];
        float4 v = *(const float4*)&src[p];
        bins[g][l0][c] += v.x; bins[g][l1][c] += v.y;
        bins[g][l2][c] += v.z; bins[g][l3][c] += v.w;
    }
    __syncthreads();

    // partials layout: [(b*2+g)*41 + l][chunk][c]
    float* pp = partials + ((size_t)((b * 2 + g) * NL) * 64 + chunk) * 128;
#pragma unroll
    for (int i = 0; i < NL; ++i)
        pp[(size_t)i * 64 * 128 + c] = bins[g][i][c];

    if (tid < NL) atomicAdd(&ghist[b * NL + tid], hist[tid]);
}

// ---------------------------------------------------------------------------
// K2b: reduce 64 chunk-partials -> sums[(b*2+g)*41 + l][128]. 656 blocks.
// ---------------------------------------------------------------------------
__global__ __launch_bounds__(128)
void k_red(const float* __restrict__ partials, float* __restrict__ sums)
{
    const int bid = (int)blockIdx.x;        // (b*2+g)*41 + l
    const int c = (int)threadIdx.x;
    const float* pp = partials + (size_t)bid * 64 * 128;
    float s = 0.f;
#pragma unroll
    for (int ch = 0; ch < 64; ++ch) s += pp[ch * 128 + c];
    sums[(size_t)bid * 128 + c] = s;
}

// ---------------------------------------------------------------------------
// K3: mean/base select + L2-normalize over classes + SE MLP -> gates.
// ---------------------------------------------------------------------------
__global__ __launch_bounds__(128)
void k_gates(const float* __restrict__ sums, const int* __restrict__ ghist,
             const float* __restrict__ base_f, const float* __restrict__ base_d,
             const float* __restrict__ f_w1, const float* __restrict__ f_w2,
             const float* __restrict__ d_w1, const float* __restrict__ d_w2,
             float* __restrict__ gates)
{
    __shared__ float sv[128];
    __shared__ float h1[8];
    const int b = (int)blockIdx.x >> 1;
    const int feat = (int)blockIdx.x & 1;
    const int c = (int)threadIdx.x;

    const float* base = feat ? base_d : base_f;
    float suma = 0.f, sumsq = 0.f;
    for (int lc = 0; lc < NL; ++lc) {
        float s = sums[(size_t)((b * 2 + feat) * NL + lc) * 128 + c];
        int cnt = ghist[b * NL + lc];
        float att = (cnt > 0) ? (s / (float)cnt) : base[(b * NL + lc) * 128 + c];
        suma += att;
        sumsq += att * att;
    }
    sv[c] = suma / fmaxf(sqrtf(sumsq), 1e-12f);
    __syncthreads();

    const float* w1 = feat ? d_w1 : f_w1;
    const float* w2 = feat ? d_w2 : f_w2;
    if (c < 8) {
        float h = 0.f;
        for (int k = 0; k < 128; ++k) h += w1[c * 128 + k] * sv[k];
        h1[c] = fmaxf(h, 0.f);
    }
    __syncthreads();

    float gv = 0.f;
#pragma unroll
    for (int o = 0; o < 8; ++o) gv += w2[c * 8 + o] * h1[o];
    gates[feat * 1024 + b * 128 + c] = 1.f / (1.f + expf(-gv));
}

// ---------------------------------------------------------------------------
// K4: out = fuse * g_f + d * g_d (fuse in-place in d_out).
// ---------------------------------------------------------------------------
__global__ __launch_bounds__(256)
void k_final(const float* __restrict__ d, const float* __restrict__ gates,
             float* out)
{
    size_t t4 = (size_t)blockIdx.x * 256 + threadIdx.x;
    size_t basei = t4 * 4;
    int bc = (int)(basei >> 14);
    float gf = gates[bc];
    float gd = gates[1024 + bc];
    float4 f = *(const float4*)(out + basei);
    float4 dv = *(const float4*)(d + basei);
    float4 o;
    o.x = f.x * gf + dv.x * gd;
    o.y = f.y * gf + dv.y * gd;
    o.z = f.z * gf + dv.z * gd;
    o.w = f.w * gf + dv.w * gd;
    *(float4*)(out + basei) = o;
}

extern "C" void kernel_launch(void* const* d_in, const int* in_sizes, int n_in,
                              void* d_out, int out_size, void* d_ws, size_t ws_size,
                              hipStream_t stream)
{
    (void)in_sizes; (void)n_in; (void)out_size; (void)ws_size;
    const float* r      = (const float*)d_in[0];
    const float* d      = (const float*)d_in[1];
    const int*   label  = (const int*)d_in[2];
    const float* conv_w = (const float*)d_in[3];
    const float* f_w1   = (const float*)d_in[4];
    const float* f_w2   = (const float*)d_in[5];
    const float* d_w1   = (const float*)d_in[6];
    const float* d_w2   = (const float*)d_in[7];
    const float* base_f = (const float*)d_in[8];
    const float* base_d = (const float*)d_in[9];
    float* out = (float*)d_out;

    char* ws = (char*)d_ws;
    u16* nhwc       = (u16*)(ws + NHWC_OFF);
    float* partials = (float*)(ws + PART_OFF);
    float* sums     = (float*)(ws + SUMS_OFF);
    u16* wa         = (u16*)(ws + WA_OFF);
    int* ghist      = (int*)(ws + GHIST_OFF);
    float* gates    = (float*)(ws + GATES_OFF);

    hipLaunchKernelGGL(k_prep, dim3(2048), dim3(256), 0, stream, r, d, nhwc);
    hipLaunchKernelGGL(k_wpack, dim3(576), dim3(64), 0, stream, conv_w, wa, ghist);
    hipLaunchKernelGGL(k_conv, dim3(1024), dim3(256), 0, stream, nhwc, wa, out);
    hipLaunchKernelGGL(k_seg, dim3(512), dim3(256), 0, stream, out, d, label,
                       partials, ghist);
    hipLaunchKernelGGL(k_red, dim3(656), dim3(128), 0, stream, partials, sums);
    hipLaunchKernelGGL(k_gates, dim3(16), dim3(128), 0, stream, sums, ghist,
                       base_f, base_d, f_w1, f_w2, d_w1, d_w2, gates);
    hipLaunchKernelGGL(k_final, dim3(16384), dim3(256), 0, stream, d, gates, out);
}